// Round 7
// baseline (136.464 us; speedup 1.0000x reference)
//
#include <hip/hip_runtime.h>

// Problem constants
#define Vn 128
#define Sn 32
#define En 16
#define M0 128
#define Ln 128
#define Bn 16
#define Nn 127
#define NROWS (Bn * Nn)     // 2032 blocks, one row each
#define RS 20               // sb table row stride (dwords), 16B-aligned
// workspace layout (floats)
#define WS_UO 0             // [2032][16]
#define WS_UG 32768         // [16][16]
#define WS_CC 33024         // [16]

__global__ __launch_bounds__(256, 8) void memnet_core(
    const float* __restrict__ node_fts, const float* __restrict__ edge_fts,
    const float* __restrict__ graph_fts, const float* __restrict__ adjm,
    const float* __restrict__ enc, const float* __restrict__ qb,
    const float* __restrict__ sb, const float* __restrict__ ob,
    const float* __restrict__ mc, float* __restrict__ ws)
{
    __shared__ __align__(16) float sbL[M0 * RS];    // sb rows (row 127 = nil zeros)
    __shared__ __align__(16) float encL[Sn * En];
    __shared__ unsigned int idxw[M0 * 8];           // 32 uint8 idx per slot, packed
    __shared__ float scoresL[M0];
    __shared__ float probsL[M0];
    __shared__ float uL[En];
    __shared__ float ugL[En];
    __shared__ float cM[En];    // sb[0][e] * sum_s enc[s][e]
    __shared__ float cC[En];    // ob[0][e] * sum_s enc[s][e]
    __shared__ float owaveL[4 * En];
    __shared__ float red[4], red2[4];
    __shared__ int listL[128];
    __shared__ int flagL[128];
    __shared__ int wcnt[2];

    const int t = threadIdx.x;
    const int bt = blockIdx.x;          // output row == b*127 + i
    const int b = bt / 127;
    const int lane = t & 63;
    const int wv = t >> 6;

    // ---- stage sb table into LDS (ob stays in L1/L2 — read directly in gather) ----
    for (int c = t; c < 512; c += 256) {
        int r = c >> 2, q = c & 3;
        float4 v = make_float4(0.f, 0.f, 0.f, 0.f);
        if (r < 127) v = *(const float4*)&sb[r * 16 + q * 4];
        *(float4*)&sbL[r * RS + q * 4] = v;
    }
    if (t < 128) *(float4*)&encL[t * 4] = *(const float4*)&enc[t * 4];

    // ---- active flags + ballot-compacted slot list ----
    if (t < 128) {
        bool flag = (t < 127) && (adjm[(size_t)bt * 127 + t] != 0.f);
        unsigned long long msk = __ballot(flag);
        int pos = (int)__popcll(msk & ((1ull << lane) - 1ull));
        if (flag) listL[(t & 64) + pos] = t;   // wave0 -> [0..), wave1 -> [64..)
        if (lane == 0) wcnt[t >> 6] = (int)__popcll(msk);
        flagL[t] = flag ? 1 : 0;
    }
    // ---- index tile for active slots only (coalesced streaming read) ----
    for (int c = t; c < 1024; c += 256) {
        int m = c >> 3, q = c & 7;
        if (m < 127 && adjm[(size_t)bt * 127 + m] != 0.f) {
            float4 v = *(const float4*)&edge_fts[(size_t)(bt * 127 + m) * 32 + q * 4];
            idxw[m * 8 + q] = (unsigned)(int)v.x | ((unsigned)(int)v.y << 8)
                            | ((unsigned)(int)v.z << 16) | ((unsigned)(int)v.w << 24);
        }
    }
    // ---- u (wave0), u_g (wave2), cM/cC (wave1) ----
    if (lane < 16) {
        if (wv == 0) {
            float ue = 0.f;
            for (int s = 0; s < 32; s++) {
                int qi = (int)node_fts[(size_t)bt * 32 + s];
                if (qi < 0) qi = 0;
                float w = (qi < 127) ? qb[qi * 16 + lane] : 0.f;
                ue = fmaf(w, enc[s * 16 + lane], ue);
            }
            uL[lane] = ue;
        } else if (wv == 2) {
            float ue = 0.f;
            for (int s = 0; s < 32; s++) {
                int qi = (int)graph_fts[b * 32 + s];
                if (qi < 0) qi = 0;
                float w = (qi < 127) ? qb[qi * 16 + lane] : 0.f;
                ue = fmaf(w, enc[s * 16 + lane], ue);
            }
            ugL[lane] = ue;
        } else if (wv == 1) {
            float es = 0.f;
            for (int s = 0; s < 32; s++) es += enc[s * 16 + lane];
            cM[lane] = sb[lane] * es;   // vocab row 0
            cC[lane] = ob[lane] * es;
        }
    }
    __syncthreads();

    // ---- masked/pad slots: closed-form scores ----
    if (t < 128 && !flagL[t]) {
        float p = 0.f;
#pragma unroll
        for (int e4 = 0; e4 < 16; e4 += 4) {
            float4 m4 = *(const float4*)&mc[t * 16 + e4];
            p = fmaf(cM[e4 + 0] + m4.x, uL[e4 + 0], p);
            p = fmaf(cM[e4 + 1] + m4.y, uL[e4 + 1], p);
            p = fmaf(cM[e4 + 2] + m4.z, uL[e4 + 2], p);
            p = fmaf(cM[e4 + 3] + m4.w, uL[e4 + 3], p);
        }
        scoresL[t] = p;
    }

    // ---- gather: one active slot per quad; sb from LDS, ob from L1/global ----
    const int eg4 = (t & 3) * 4;
    const int qd = t >> 2;              // quad id 0..63
    const int c0 = wcnt[0];
    const int nact = c0 + wcnt[1];
    const float4 u4 = *(const float4*)&uL[eg4];

    float4 aC_A = make_float4(0.f, 0.f, 0.f, 0.f);
    float4 aC_B = make_float4(0.f, 0.f, 0.f, 0.f);
    int mA = -1, mB = -1;

    if (qd < nact) {
        mA = listL[(qd < c0) ? qd : (qd - c0 + 64)];
        float4 aM = make_float4(0.f, 0.f, 0.f, 0.f);
        for (int sq = 0; sq < 8; sq++) {
            unsigned w0 = idxw[mA * 8 + sq];
#pragma unroll
            for (int j = 0; j < 4; j++) {
                int s = sq * 4 + j;
                int i0 = (w0 >> (8 * j)) & 0xFF;
                int i0c = (i0 < 127) ? i0 : 126;            // clamp for in-bounds load
                float4 eb = *(const float4*)&encL[s * 16 + eg4];
                float4 a0 = *(const float4*)&sbL[i0 * RS + eg4];
                float4 cv = *(const float4*)&ob[i0c * 16 + eg4];  // L1-resident (8 KB)
                if (i0 == 127) cv = make_float4(0.f, 0.f, 0.f, 0.f);  // nil row
                aM.x = fmaf(a0.x, eb.x, aM.x); aM.y = fmaf(a0.y, eb.y, aM.y);
                aM.z = fmaf(a0.z, eb.z, aM.z); aM.w = fmaf(a0.w, eb.w, aM.w);
                aC_A.x = fmaf(cv.x, eb.x, aC_A.x); aC_A.y = fmaf(cv.y, eb.y, aC_A.y);
                aC_A.z = fmaf(cv.z, eb.z, aC_A.z); aC_A.w = fmaf(cv.w, eb.w, aC_A.w);
            }
        }
        float4 mc4 = *(const float4*)&mc[mA * 16 + eg4];
        float p = (aM.x + mc4.x) * u4.x + (aM.y + mc4.y) * u4.y
                + (aM.z + mc4.z) * u4.z + (aM.w + mc4.w) * u4.w;
        p += __shfl_xor(p, 1); p += __shfl_xor(p, 2);
        if ((t & 3) == 0) scoresL[mA] = p;
    }
    if (qd + 64 < nact) {   // overflow slots (nact > 64)
        int g = qd + 64;
        mB = listL[(g < c0) ? g : (g - c0 + 64)];
        float4 aM = make_float4(0.f, 0.f, 0.f, 0.f);
        for (int sq = 0; sq < 8; sq++) {
            unsigned w0 = idxw[mB * 8 + sq];
#pragma unroll
            for (int j = 0; j < 4; j++) {
                int s = sq * 4 + j;
                int i0 = (w0 >> (8 * j)) & 0xFF;
                int i0c = (i0 < 127) ? i0 : 126;
                float4 eb = *(const float4*)&encL[s * 16 + eg4];
                float4 a0 = *(const float4*)&sbL[i0 * RS + eg4];
                float4 cv = *(const float4*)&ob[i0c * 16 + eg4];
                if (i0 == 127) cv = make_float4(0.f, 0.f, 0.f, 0.f);
                aM.x = fmaf(a0.x, eb.x, aM.x); aM.y = fmaf(a0.y, eb.y, aM.y);
                aM.z = fmaf(a0.z, eb.z, aM.z); aM.w = fmaf(a0.w, eb.w, aM.w);
                aC_B.x = fmaf(cv.x, eb.x, aC_B.x); aC_B.y = fmaf(cv.y, eb.y, aC_B.y);
                aC_B.z = fmaf(cv.z, eb.z, aC_B.z); aC_B.w = fmaf(cv.w, eb.w, aC_B.w);
            }
        }
        float4 mc4 = *(const float4*)&mc[mB * 16 + eg4];
        float p = (aM.x + mc4.x) * u4.x + (aM.y + mc4.y) * u4.y
                + (aM.z + mc4.z) * u4.z + (aM.w + mc4.w) * u4.w;
        p += __shfl_xor(p, 1); p += __shfl_xor(p, 2);
        if ((t & 3) == 0) scoresL[mB] = p;
    }
    __syncthreads();

    // ---- softmax over 128 slots (+ masked prob mass in same reduction) ----
    float pmask;
    {
        float v = (t < 128) ? scoresL[t] : -1e30f;
#pragma unroll
        for (int off = 32; off > 0; off >>= 1) v = fmaxf(v, __shfl_xor(v, off));
        if (lane == 0) red[wv] = v;
        __syncthreads();
        float mx = fmaxf(fmaxf(red[0], red[1]), fmaxf(red[2], red[3]));
        float ex = (t < 128) ? __expf(scoresL[t] - mx) : 0.f;
        float exm = (t < 128 && !flagL[t]) ? ex : 0.f;
        float sv = ex, sm = exm;
#pragma unroll
        for (int off = 32; off > 0; off >>= 1) {
            sv += __shfl_xor(sv, off);
            sm += __shfl_xor(sm, off);
        }
        __syncthreads();
        if (lane == 0) { red[wv] = sv; red2[wv] = sm; }
        __syncthreads();
        float sum = red[0] + red[1] + red[2] + red[3];
        pmask = (red2[0] + red2[1] + red2[2] + red2[3]) / sum;
        if (t < 128) probsL[t] = ex / sum;
    }
    __syncthreads();

    // ---- o_active: probs-weighted Cj from registers, shfl-tree reduce ----
    {
        float4 op = make_float4(0.f, 0.f, 0.f, 0.f);
        if (mA >= 0) {
            float pa = probsL[mA];
            op.x = pa * aC_A.x; op.y = pa * aC_A.y;
            op.z = pa * aC_A.z; op.w = pa * aC_A.w;
        }
        if (mB >= 0) {
            float pb = probsL[mB];
            op.x = fmaf(pb, aC_B.x, op.x); op.y = fmaf(pb, aC_B.y, op.y);
            op.z = fmaf(pb, aC_B.z, op.z); op.w = fmaf(pb, aC_B.w, op.w);
        }
#pragma unroll
        for (int off = 4; off <= 32; off <<= 1) {
            op.x += __shfl_xor(op.x, off);
            op.y += __shfl_xor(op.y, off);
            op.z += __shfl_xor(op.z, off);
            op.w += __shfl_xor(op.w, off);
        }
        if (lane < 4) *(float4*)&owaveL[wv * 16 + lane * 4] = op;
    }
    __syncthreads();
    // ---- write uo / ug / cC to workspace (epilogue moved to memnet_tail) ----
    if (t < 16) {
        float o = owaveL[t] + owaveL[16 + t] + owaveL[32 + t] + owaveL[48 + t];
        ws[WS_UO + bt * 16 + t] = uL[t] + o + cC[t] * pmask;
        if (bt % 127 == 0) ws[WS_UG + b * 16 + t] = ugL[t];
        if (bt == 0) ws[WS_CC + t] = cC[t];
    }
}

// Tail: x = relu(uo @ W_out); xg = relu((ug + cC) @ W_out);
//       out[b,i,:] = (x_row + xg) @ W_fin     (== ret + ret127)
// grid: 16 batches x 8 row-chunks of 16
__global__ __launch_bounds__(256, 8) void memnet_tail(
    const float* __restrict__ ws, const float* __restrict__ wout,
    const float* __restrict__ wfin, float* __restrict__ out)
{
    __shared__ __align__(16) float woutL[16 * 128];   // 8 KB
    __shared__ float xsum[16][130];                   // x + xg, padded stride
    __shared__ float uoT[16][16];
    __shared__ float xgV[128];
    __shared__ float ugcc[16];

    const int t = threadIdx.x;
    const int b = blockIdx.x >> 3;
    const int c = blockIdx.x & 7;
    const int i0 = c * 16;

    // stage wout
    {
        const float4* src = (const float4*)wout;
        float4* dst = (float4*)woutL;
        dst[t] = src[t];
        dst[t + 256] = src[t + 256];
    }
    // stage uo tile; ug + cC
    {
        int r = t >> 4, e = t & 15;
        int i = i0 + r;
        uoT[r][e] = (i < 127) ? ws[WS_UO + (size_t)(b * 127 + i) * 16 + e] : 0.f;
        if (t < 16) ugcc[t] = ws[WS_UG + b * 16 + t] + ws[WS_CC + t];
    }
    __syncthreads();
    // xg[l] = relu(sum_e ugcc[e] * wout[e][l])
    if (t < 128) {
        float acc = 0.f;
#pragma unroll
        for (int e = 0; e < 16; e++) acc = fmaf(ugcc[e], woutL[e * 128 + t], acc);
        xgV[t] = fmaxf(acc, 0.f);
    }
    __syncthreads();
    // xsum[r][l] = relu(uo[r] @ wout[:,l]) + xg[l]   (8 l per thread)
    {
        int r = t >> 4;
#pragma unroll
        for (int k = 0; k < 8; k++) {
            int l = (t & 15) + 16 * k;
            float acc = 0.f;
#pragma unroll
            for (int e = 0; e < 16; e++) acc = fmaf(uoT[r][e], woutL[e * 128 + l], acc);
            xsum[r][l] = fmaxf(acc, 0.f) + xgV[l];
        }
    }
    __syncthreads();
    // out row GEMV: thread owns (row r = t>>4, 8 cols v0 = (t&15)*8)
    {
        int r = t >> 4, v0 = (t & 15) * 8;
        int i = i0 + r;
        float acc[8] = {0.f, 0.f, 0.f, 0.f, 0.f, 0.f, 0.f, 0.f};
        for (int l = 0; l < 128; l++) {
            float s = xsum[r][l];
            const float4 w0 = *(const float4*)&wfin[l * 128 + v0];
            const float4 w1 = *(const float4*)&wfin[l * 128 + v0 + 4];
            acc[0] = fmaf(s, w0.x, acc[0]); acc[1] = fmaf(s, w0.y, acc[1]);
            acc[2] = fmaf(s, w0.z, acc[2]); acc[3] = fmaf(s, w0.w, acc[3]);
            acc[4] = fmaf(s, w1.x, acc[4]); acc[5] = fmaf(s, w1.y, acc[5]);
            acc[6] = fmaf(s, w1.z, acc[6]); acc[7] = fmaf(s, w1.w, acc[7]);
        }
        if (i < 127) {
            float4* o0 = (float4*)&out[((size_t)(b * 127 + i)) * 128 + v0];
            o0[0] = make_float4(acc[0], acc[1], acc[2], acc[3]);
            o0[1] = make_float4(acc[4], acc[5], acc[6], acc[7]);
        }
    }
}

extern "C" void kernel_launch(void* const* d_in, const int* in_sizes, int n_in,
                              void* d_out, int out_size, void* d_ws, size_t ws_size,
                              hipStream_t stream)
{
    const float* node  = (const float*)d_in[0];
    const float* edge  = (const float*)d_in[1];
    const float* graph = (const float*)d_in[2];
    const float* adjm  = (const float*)d_in[3];
    // d_in[4] = hidden (unused)
    const float* enc   = (const float*)d_in[5];
    const float* qb    = (const float*)d_in[6];
    const float* sb    = (const float*)d_in[7];
    const float* ob    = (const float*)d_in[8];
    const float* mc    = (const float*)d_in[9];
    // d_in[10] = W_int (unused, num_hops == 1)
    const float* wout  = (const float*)d_in[11];
    const float* wfin  = (const float*)d_in[12];

    float* ws = (float*)d_ws;   // ~132 KB used

    memnet_core<<<NROWS, 256, 0, stream>>>(node, edge, graph, adjm, enc, qb,
                                           sb, ob, mc, ws);
    memnet_tail<<<Bn * 8, 256, 0, stream>>>(ws, wout, wfin, (float*)d_out);
}

// Round 8
// 132.124 us; speedup vs baseline: 1.0329x; 1.0329x over previous
//
#include <hip/hip_runtime.h>

// Problem constants
#define Vn 128
#define Sn 32
#define En 16
#define M0 128
#define Ln 128
#define Bn 16
#define Nn 127
#define NROWS (Bn * Nn)     // 2032 blocks, one row each
#define RS 20               // sb table row stride (dwords), 16B-aligned
// workspace layout (floats)
#define WS_UO 0             // [2032][16]
#define WS_UG 32768         // [16][16]
#define WS_CC 33024         // [16]

__global__ __launch_bounds__(256, 8) void memnet_core(
    const float* __restrict__ node_fts, const float* __restrict__ edge_fts,
    const float* __restrict__ graph_fts, const float* __restrict__ adjm,
    const float* __restrict__ enc, const float* __restrict__ qb,
    const float* __restrict__ sb, const float* __restrict__ ob,
    const float* __restrict__ mc, float* __restrict__ ws)
{
    __shared__ __align__(16) float sbL[M0 * RS];    // sb rows (row 127 = nil zeros)
    __shared__ __align__(16) float encL[Sn * En];
    __shared__ unsigned int idxw[M0 * 8];           // 32 uint8 idx per slot, packed
    __shared__ float scoresL[M0];
    __shared__ float uL[En];
    __shared__ float ugL[En];
    __shared__ float cM[En];    // sb[0][e] * sum_s enc[s][e]
    __shared__ float cC[En];    // ob[0][e] * sum_s enc[s][e]
    __shared__ float owaveL[4 * En];
    __shared__ int listL[128];
    __shared__ int flagL[128];
    __shared__ int wcnt[2];

    const int t = threadIdx.x;
    const int bt = blockIdx.x;          // output row == b*127 + i
    const int b = bt / 127;
    const int lane = t & 63;
    const int wv = t >> 6;

    // ================= phase 1: staging + flags + u/ug/cM (1 barrier) =================
    // stage sb table into LDS (ob stays in L1/L2 — read directly in gather)
    for (int c = t; c < 512; c += 256) {
        int r = c >> 2, q = c & 3;
        float4 v = make_float4(0.f, 0.f, 0.f, 0.f);
        if (r < 127) v = *(const float4*)&sb[r * 16 + q * 4];
        *(float4*)&sbL[r * RS + q * 4] = v;
    }
    if (t < 128) *(float4*)&encL[t * 4] = *(const float4*)&enc[t * 4];

    // active flags + ballot-compacted slot list
    if (t < 128) {
        bool flag = (t < 127) && (adjm[(size_t)bt * 127 + t] != 0.f);
        unsigned long long msk = __ballot(flag);
        int pos = (int)__popcll(msk & ((1ull << lane) - 1ull));
        if (flag) listL[(t & 64) + pos] = t;   // wave0 -> [0..), wave1 -> [64..)
        if (lane == 0) wcnt[t >> 6] = (int)__popcll(msk);
        flagL[t] = flag ? 1 : 0;
    }
    // index tile for active slots only (coalesced streaming read)
    for (int c = t; c < 1024; c += 256) {
        int m = c >> 3, q = c & 7;
        if (m < 127 && adjm[(size_t)bt * 127 + m] != 0.f) {
            float4 v = *(const float4*)&edge_fts[(size_t)(bt * 127 + m) * 32 + q * 4];
            idxw[m * 8 + q] = (unsigned)(int)v.x | ((unsigned)(int)v.y << 8)
                            | ((unsigned)(int)v.z << 16) | ((unsigned)(int)v.w << 24);
        }
    }
    // u (wave0) / u_g (wave2) / cM,cC (wave1) — parallelized over s (4 groups x 8)
    {
        const int e = lane & 15, sg = lane >> 4;
        if (wv == 0) {
            float ue = 0.f;
#pragma unroll
            for (int k = 0; k < 8; k++) {
                int s = sg + 4 * k;
                int qi = (int)node_fts[(size_t)bt * 32 + s];
                if (qi < 0) qi = 0;
                float w = (qi < 127) ? qb[qi * 16 + e] : 0.f;
                ue = fmaf(w, enc[s * 16 + e], ue);
            }
            ue += __shfl_xor(ue, 16);
            ue += __shfl_xor(ue, 32);
            if (lane < 16) uL[e] = ue;
        } else if (wv == 2) {
            float ue = 0.f;
#pragma unroll
            for (int k = 0; k < 8; k++) {
                int s = sg + 4 * k;
                int qi = (int)graph_fts[b * 32 + s];
                if (qi < 0) qi = 0;
                float w = (qi < 127) ? qb[qi * 16 + e] : 0.f;
                ue = fmaf(w, enc[s * 16 + e], ue);
            }
            ue += __shfl_xor(ue, 16);
            ue += __shfl_xor(ue, 32);
            if (lane < 16) ugL[e] = ue;
        } else if (wv == 1) {
            float es = 0.f;
#pragma unroll
            for (int k = 0; k < 8; k++) es += enc[(sg + 4 * k) * 16 + e];
            es += __shfl_xor(es, 16);
            es += __shfl_xor(es, 32);
            if (lane < 16) { cM[e] = sb[e] * es; cC[e] = ob[e] * es; }
        }
    }
    __syncthreads();

    // ================= phase 2: scores (masked closed-form + active gather) =================
    if (t < 128 && !flagL[t]) {
        float p = 0.f;
#pragma unroll
        for (int e4 = 0; e4 < 16; e4 += 4) {
            float4 m4 = *(const float4*)&mc[t * 16 + e4];
            p = fmaf(cM[e4 + 0] + m4.x, uL[e4 + 0], p);
            p = fmaf(cM[e4 + 1] + m4.y, uL[e4 + 1], p);
            p = fmaf(cM[e4 + 2] + m4.z, uL[e4 + 2], p);
            p = fmaf(cM[e4 + 3] + m4.w, uL[e4 + 3], p);
        }
        scoresL[t] = p;
    }

    const int eg4 = (t & 3) * 4;
    const int qd = t >> 2;              // quad id 0..63
    const int c0 = wcnt[0];
    const int nact = c0 + wcnt[1];
    const float4 u4 = *(const float4*)&uL[eg4];

    float4 aC_A = make_float4(0.f, 0.f, 0.f, 0.f);
    float4 aC_B = make_float4(0.f, 0.f, 0.f, 0.f);
    int mA = -1, mB = -1;

    if (qd < nact) {
        mA = listL[(qd < c0) ? qd : (qd - c0 + 64)];
        float4 aM = make_float4(0.f, 0.f, 0.f, 0.f);
        for (int sq = 0; sq < 8; sq++) {
            unsigned w0 = idxw[mA * 8 + sq];
#pragma unroll
            for (int j = 0; j < 4; j++) {
                int s = sq * 4 + j;
                int i0 = (w0 >> (8 * j)) & 0xFF;
                int i0c = (i0 < 127) ? i0 : 126;            // clamp for in-bounds load
                float4 eb = *(const float4*)&encL[s * 16 + eg4];
                float4 a0 = *(const float4*)&sbL[i0 * RS + eg4];
                float4 cv = *(const float4*)&ob[i0c * 16 + eg4];  // L1-resident (8 KB)
                if (i0 == 127) cv = make_float4(0.f, 0.f, 0.f, 0.f);  // nil row
                aM.x = fmaf(a0.x, eb.x, aM.x); aM.y = fmaf(a0.y, eb.y, aM.y);
                aM.z = fmaf(a0.z, eb.z, aM.z); aM.w = fmaf(a0.w, eb.w, aM.w);
                aC_A.x = fmaf(cv.x, eb.x, aC_A.x); aC_A.y = fmaf(cv.y, eb.y, aC_A.y);
                aC_A.z = fmaf(cv.z, eb.z, aC_A.z); aC_A.w = fmaf(cv.w, eb.w, aC_A.w);
            }
        }
        float4 mc4 = *(const float4*)&mc[mA * 16 + eg4];
        float p = (aM.x + mc4.x) * u4.x + (aM.y + mc4.y) * u4.y
                + (aM.z + mc4.z) * u4.z + (aM.w + mc4.w) * u4.w;
        p += __shfl_xor(p, 1); p += __shfl_xor(p, 2);
        if ((t & 3) == 0) scoresL[mA] = p;
    }
    if (qd + 64 < nact) {   // overflow slots (nact > 64)
        int g = qd + 64;
        mB = listL[(g < c0) ? g : (g - c0 + 64)];
        float4 aM = make_float4(0.f, 0.f, 0.f, 0.f);
        for (int sq = 0; sq < 8; sq++) {
            unsigned w0 = idxw[mB * 8 + sq];
#pragma unroll
            for (int j = 0; j < 4; j++) {
                int s = sq * 4 + j;
                int i0 = (w0 >> (8 * j)) & 0xFF;
                int i0c = (i0 < 127) ? i0 : 126;
                float4 eb = *(const float4*)&encL[s * 16 + eg4];
                float4 a0 = *(const float4*)&sbL[i0 * RS + eg4];
                float4 cv = *(const float4*)&ob[i0c * 16 + eg4];
                if (i0 == 127) cv = make_float4(0.f, 0.f, 0.f, 0.f);
                aM.x = fmaf(a0.x, eb.x, aM.x); aM.y = fmaf(a0.y, eb.y, aM.y);
                aM.z = fmaf(a0.z, eb.z, aM.z); aM.w = fmaf(a0.w, eb.w, aM.w);
                aC_B.x = fmaf(cv.x, eb.x, aC_B.x); aC_B.y = fmaf(cv.y, eb.y, aC_B.y);
                aC_B.z = fmaf(cv.z, eb.z, aC_B.z); aC_B.w = fmaf(cv.w, eb.w, aC_B.w);
            }
        }
        float4 mc4 = *(const float4*)&mc[mB * 16 + eg4];
        float p = (aM.x + mc4.x) * u4.x + (aM.y + mc4.y) * u4.y
                + (aM.z + mc4.z) * u4.z + (aM.w + mc4.w) * u4.w;
        p += __shfl_xor(p, 1); p += __shfl_xor(p, 2);
        if ((t & 3) == 0) scoresL[mB] = p;
    }
    __syncthreads();

    // ============ phase 3: wave-redundant softmax + o partials (no inner barriers) ============
    float pmask;
    {
        float v1 = scoresL[lane], v2 = scoresL[lane + 64];
        int f1 = flagL[lane], f2 = flagL[lane + 64];
        float mv = fmaxf(v1, v2);
#pragma unroll
        for (int off = 32; off > 0; off >>= 1) mv = fmaxf(mv, __shfl_xor(mv, off));
        float e1 = __expf(v1 - mv), e2 = __expf(v2 - mv);
        float sv = e1 + e2;
        float sm = (f1 ? 0.f : e1) + (f2 ? 0.f : e2);
#pragma unroll
        for (int off = 32; off > 0; off >>= 1) {
            sv += __shfl_xor(sv, off);
            sm += __shfl_xor(sm, off);
        }
        pmask = sm / sv;

        float4 op = make_float4(0.f, 0.f, 0.f, 0.f);
        if (mA >= 0) {
            float pa = __expf(scoresL[mA] - mv) / sv;   // quad-uniform LDS broadcast
            op.x = pa * aC_A.x; op.y = pa * aC_A.y;
            op.z = pa * aC_A.z; op.w = pa * aC_A.w;
        }
        if (mB >= 0) {
            float pb = __expf(scoresL[mB] - mv) / sv;
            op.x = fmaf(pb, aC_B.x, op.x); op.y = fmaf(pb, aC_B.y, op.y);
            op.z = fmaf(pb, aC_B.z, op.z); op.w = fmaf(pb, aC_B.w, op.w);
        }
#pragma unroll
        for (int off = 4; off <= 32; off <<= 1) {
            op.x += __shfl_xor(op.x, off);
            op.y += __shfl_xor(op.y, off);
            op.z += __shfl_xor(op.z, off);
            op.w += __shfl_xor(op.w, off);
        }
        if (lane < 4) *(float4*)&owaveL[wv * 16 + lane * 4] = op;
    }
    __syncthreads();

    // ================= phase 4: combine + workspace write =================
    if (t < 16) {
        float o = owaveL[t] + owaveL[16 + t] + owaveL[32 + t] + owaveL[48 + t];
        ws[WS_UO + bt * 16 + t] = uL[t] + o + cC[t] * pmask;
        if (bt % 127 == 0) ws[WS_UG + b * 16 + t] = ugL[t];
        if (bt == 0) ws[WS_CC + t] = cC[t];
    }
}

// Tail: x = relu(uo @ W_out); xg = relu((ug + cC) @ W_out);
//       out[b,i,:] = (x_row + xg) @ W_fin     (== ret + ret127)
// grid: 16 batches x 8 row-chunks of 16
__global__ __launch_bounds__(256, 8) void memnet_tail(
    const float* __restrict__ ws, const float* __restrict__ wout,
    const float* __restrict__ wfin, float* __restrict__ out)
{
    __shared__ __align__(16) float woutL[16 * 128];   // 8 KB
    __shared__ float xsum[16][130];                   // x + xg, padded stride
    __shared__ float uoT[16][16];
    __shared__ float xgV[128];
    __shared__ float ugcc[16];

    const int t = threadIdx.x;
    const int b = blockIdx.x >> 3;
    const int c = blockIdx.x & 7;
    const int i0 = c * 16;

    // stage wout
    {
        const float4* src = (const float4*)wout;
        float4* dst = (float4*)woutL;
        dst[t] = src[t];
        dst[t + 256] = src[t + 256];
    }
    // stage uo tile; ug + cC
    {
        int r = t >> 4, e = t & 15;
        int i = i0 + r;
        uoT[r][e] = (i < 127) ? ws[WS_UO + (size_t)(b * 127 + i) * 16 + e] : 0.f;
        if (t < 16) ugcc[t] = ws[WS_UG + b * 16 + t] + ws[WS_CC + t];
    }
    __syncthreads();
    // xg[l] = relu(sum_e ugcc[e] * wout[e][l])
    if (t < 128) {
        float acc = 0.f;
#pragma unroll
        for (int e = 0; e < 16; e++) acc = fmaf(ugcc[e], woutL[e * 128 + t], acc);
        xgV[t] = fmaxf(acc, 0.f);
    }
    __syncthreads();
    // xsum[r][l] = relu(uo[r] @ wout[:,l]) + xg[l]   (8 l per thread)
    {
        int r = t >> 4;
#pragma unroll
        for (int k = 0; k < 8; k++) {
            int l = (t & 15) + 16 * k;
            float acc = 0.f;
#pragma unroll
            for (int e = 0; e < 16; e++) acc = fmaf(uoT[r][e], woutL[e * 128 + l], acc);
            xsum[r][l] = fmaxf(acc, 0.f) + xgV[l];
        }
    }
    __syncthreads();
    // out row GEMV: thread owns (row r = t>>4, 8 cols v0 = (t&15)*8)
    {
        int r = t >> 4, v0 = (t & 15) * 8;
        int i = i0 + r;
        float acc[8] = {0.f, 0.f, 0.f, 0.f, 0.f, 0.f, 0.f, 0.f};
        for (int l = 0; l < 128; l++) {
            float s = xsum[r][l];
            const float4 w0 = *(const float4*)&wfin[l * 128 + v0];
            const float4 w1 = *(const float4*)&wfin[l * 128 + v0 + 4];
            acc[0] = fmaf(s, w0.x, acc[0]); acc[1] = fmaf(s, w0.y, acc[1]);
            acc[2] = fmaf(s, w0.z, acc[2]); acc[3] = fmaf(s, w0.w, acc[3]);
            acc[4] = fmaf(s, w1.x, acc[4]); acc[5] = fmaf(s, w1.y, acc[5]);
            acc[6] = fmaf(s, w1.z, acc[6]); acc[7] = fmaf(s, w1.w, acc[7]);
        }
        if (i < 127) {
            float4* o0 = (float4*)&out[((size_t)(b * 127 + i)) * 128 + v0];
            o0[0] = make_float4(acc[0], acc[1], acc[2], acc[3]);
            o0[1] = make_float4(acc[4], acc[5], acc[6], acc[7]);
        }
    }
}

extern "C" void kernel_launch(void* const* d_in, const int* in_sizes, int n_in,
                              void* d_out, int out_size, void* d_ws, size_t ws_size,
                              hipStream_t stream)
{
    const float* node  = (const float*)d_in[0];
    const float* edge  = (const float*)d_in[1];
    const float* graph = (const float*)d_in[2];
    const float* adjm  = (const float*)d_in[3];
    // d_in[4] = hidden (unused)
    const float* enc   = (const float*)d_in[5];
    const float* qb    = (const float*)d_in[6];
    const float* sb    = (const float*)d_in[7];
    const float* ob    = (const float*)d_in[8];
    const float* mc    = (const float*)d_in[9];
    // d_in[10] = W_int (unused, num_hops == 1)
    const float* wout  = (const float*)d_in[11];
    const float* wfin  = (const float*)d_in[12];

    float* ws = (float*)d_ws;   // ~132 KB used

    memnet_core<<<NROWS, 256, 0, stream>>>(node, edge, graph, adjm, enc, qb,
                                           sb, ob, mc, ws);
    memnet_tail<<<Bn * 8, 256, 0, stream>>>(ws, wout, wfin, (float*)d_out);
}